// Round 2
// baseline (172.475 us; speedup 1.0000x reference)
//
#include <hip/hip_runtime.h>
#include <math.h>

#define NN 8192
#define CF 192
#define KNN 9
#define NSPL 8
#define PKS 12   // padded partial-list stride (16B-aligned for float4 preloads)

typedef __bf16 v8bf __attribute__((ext_vector_type(8)));
typedef float f32x16 __attribute__((ext_vector_type(16)));
typedef float f32x4 __attribute__((ext_vector_type(4)));

__device__ __forceinline__ int group_start(int g) {
    // smallest i with batch[i]==g :  ceil(8191*g/8), capped at 8192
    int s = (8191 * g + 7) >> 3;
    return s > 8192 ? 8192 : s;
}

__device__ __forceinline__ float disf(int d) {
    return d > 0 ? 1.0f / sqrtf((float)d) : 0.0f;
}

__device__ __forceinline__ unsigned short f2bf(float f) {
    unsigned u = __float_as_uint(f);
    unsigned r = (u + 0x7FFFu + ((u >> 16) & 1u)) >> 16;   // round-nearest-even
    return (unsigned short)r;
}
__device__ __forceinline__ float bf2f(unsigned short h) {
    return __uint_as_float(((unsigned)h) << 16);
}

// ---------------------------------------------------------------- transpose + split + sq
// x [8,192,32,32] -> xh/xl [8192][192] bf16 (hi/lo split, computed once).
// One block owns 64 nodes x all 192 ch -> sq computed locally; deg zeroed.
__global__ __launch_bounds__(256) void transpose_kernel(
    const float* __restrict__ x, unsigned short* __restrict__ xh,
    unsigned short* __restrict__ xl, float* __restrict__ sq,
    int* __restrict__ deg)
{
    __shared__ float tile[32][65];
    int b = blockIdx.x, ht = blockIdx.y;         // 8 x 16 blocks
    int hw0 = ht * 64;
    int tid = threadIdx.x;
    if (tid < 64) deg[(b * 16 + ht) * 64 + tid] = 0;

    float sacc[8];
#pragma unroll
    for (int p = 0; p < 8; ++p) sacc[p] = 0.0f;

    for (int ct = 0; ct < 6; ++ct) {
        int c0 = ct * 32;
        __syncthreads();
#pragma unroll
        for (int p = 0; p < 8; ++p) {
            int c  = p * 4 + (tid >> 6);
            int hw = tid & 63;
            tile[c][hw] = x[(size_t)b * 196608 + (size_t)(c0 + c) * 1024 + hw0 + hw];
        }
        __syncthreads();
#pragma unroll
        for (int p = 0; p < 8; ++p) {
            int hw = p * 8 + (tid >> 5);
            int cc = tid & 31;
            float v = tile[cc][hw];
            size_t o = (size_t)(b * 1024 + hw0 + hw) * CF + c0 + cc;
            unsigned short h = f2bf(v);
            xh[o] = h;
            xl[o] = f2bf(v - bf2f(h));
            sacc[p] = fmaf(v, v, sacc[p]);
        }
    }
#pragma unroll
    for (int p = 0; p < 8; ++p) {
        float s = sacc[p];
#pragma unroll
        for (int off = 16; off > 0; off >>= 1) s += __shfl_xor(s, off, 32);
        if ((tid & 31) == 0)
            sq[(size_t)(b * 1024 + hw0 + p * 8 + (tid >> 5))] = s;
    }
}

// ---------------------------------------------------------------- kNN partial (MFMA)
// grid: 9 groups x 16 query-blocks(64 q) x 8 candidate-splits(128 c) = 1152.
// R17 (barrier surgery; R16 counters showed knn still ~latency-bound):
//  (a) K-loop double-buffered staging -> ONE barrier per kb (was 2); depth-2
//      register prefetch (loads issued 2 iters ahead, vmcnt fully covered).
//  (b) selection: single Ds_full[64][133] dump of the whole 64x128 Gram tile
//      into the dead staging LDS (1 barrier) replaces 4 quarter-dumps
//      (8 barriers). 133-pad -> 2-way bank alias (free) on write and read.
//  (c) per-thread top-9 persists (R16); lists -> LDS once; single wave0 merge.
// C/D layout (HW-verified): col=lane&31, row=(reg&3)+8*(reg>>2)+4*(lane>>5).
// Every acc/list/slot index compile-time constant (full unroll; rule #20).
__global__ __launch_bounds__(256, 2) void knn_kernel(
    const unsigned short* __restrict__ xh, const unsigned short* __restrict__ xl,
    const float* __restrict__ sq,
    float* __restrict__ pk_d, int* __restrict__ pk_i)
{
    int bid = blockIdx.x;
    int g = bid >> 7;
    int rem = bid & 127;
    int qb = rem >> 3;
    int split = rem & 7;
    int gs = group_start(g);
    int gsize = group_start(g + 1) - gs;
    int q0 = qb * 64;
    int nq = gsize - q0; if (nq > 64) nq = 64;
    if (nq <= 0) return;                 // block-uniform; q's covered elsewhere
    int c0 = split * 128;
    int ncc = gsize - c0; if (ncc > 128) ncc = 128;

    int tid = threadIdx.x;

    if (ncc <= 0) {                      // block-uniform: empty split
        if (tid < nq) {
            int q = gs + q0 + tid;
            size_t base = ((size_t)q * NSPL + split) * PKS;
#pragma unroll
            for (int j = 0; j < KNN; ++j) { pk_d[base + j] = __builtin_inff(); pk_i[base + j] = -1; }
        }
        return;
    }

    // two 18432 B staging buffers; after the loop the region is overlaid by
    // Ds_full (34048 B) and then by the merge lists (18720 B).
    __shared__ __align__(16) char smem[36864];
    unsigned short* sm = (unsigned short*)smem;
    // short-offsets within one buffer (9216 shorts):
    //   Ah[64][24] @0, Al @1536, Bh[128][24] @3072, Bl @6144
    __shared__ float sqc_s[128];
    __shared__ float sqq_s[64];

    int lane = tid & 63, w = tid >> 6;
    int arow = (w & 1) * 32 + (lane & 31);
    int k8 = (lane >> 5) * 8;
    int brow0 = (w >> 1) * 64 + (lane & 31);

    if (tid < 64) {
        int qo = q0 + tid; if (qo > gsize - 1) qo = gsize - 1;
        sqq_s[tid] = sq[gs + qo];
    }
    if (tid < 128) {
        sqc_s[tid] = (tid < ncc) ? sq[gs + c0 + tid] : __builtin_inff();
    }

    // per-thread staging roles (fixed across kb)
    int a_hl = tid >> 7, a_r = (tid >> 1) & 63, a_half = tid & 1;
    int a_qo = q0 + a_r; if (a_qo > gsize - 1) a_qo = gsize - 1;
    const unsigned short* a_src = (a_hl ? xl : xh)
        + (size_t)(gs + a_qo) * CF + a_half * 8;
    int a_off = a_hl * 1536 + a_r * 24 + a_half * 8;

    int b_r = (tid >> 1) & 127, b_half = tid & 1;
    int b_co = c0 + b_r; if (b_co > gsize - 1) b_co = gsize - 1;
    const unsigned short* b_src0 = xh + (size_t)(gs + b_co) * CF + b_half * 8;
    const unsigned short* b_src1 = xl + (size_t)(gs + b_co) * CF + b_half * 8;
    int b_off0 = 3072 + b_r * 24 + b_half * 8;
    int b_off1 = 6144 + b_r * 24 + b_half * 8;

    f32x16 acc[2];
#pragma unroll
    for (int t = 0; t < 2; ++t)
#pragma unroll
        for (int r = 0; r < 16; ++r) acc[t][r] = 0.0f;

    // depth-2 prefetch slots: slot p holds kb-data with kb&1==p.
    uint4 sA[2], sB0[2], sB1[2];
    sA[0]  = *(const uint4*)(a_src);       sA[1]  = *(const uint4*)(a_src + 16);
    sB0[0] = *(const uint4*)(b_src0);      sB0[1] = *(const uint4*)(b_src0 + 16);
    sB1[0] = *(const uint4*)(b_src1);      sB1[1] = *(const uint4*)(b_src1 + 16);
    // write kb0 into buf0, then refill slot0 with kb2
    *(uint4*)(sm + a_off)  = sA[0];
    *(uint4*)(sm + b_off0) = sB0[0];
    *(uint4*)(sm + b_off1) = sB1[0];
    sA[0]  = *(const uint4*)(a_src  + 32);
    sB0[0] = *(const uint4*)(b_src0 + 32);
    sB1[0] = *(const uint4*)(b_src1 + 32);
    __syncthreads();

    // invariant at top of iter kb: buf[kb&1] holds kb; slot[(kb+1)&1] holds
    // kb+1; slot[kb&1] holds kb+2.  ONE barrier per iteration.
#pragma unroll
    for (int kb = 0; kb < 12; ++kb) {
        const int cur = kb & 1, nxt = cur ^ 1;
        if (kb < 11) {                   // publish kb+1 (vmcnt covered, 2 iters old)
            *(uint4*)(sm + nxt * 9216 + a_off)  = sA[nxt];
            *(uint4*)(sm + nxt * 9216 + b_off0) = sB0[nxt];
            *(uint4*)(sm + nxt * 9216 + b_off1) = sB1[nxt];
        }
        if (kb < 9) {                    // issue kb+3
            sA[nxt]  = *(const uint4*)(a_src  + (kb + 3) * 16);
            sB0[nxt] = *(const uint4*)(b_src0 + (kb + 3) * 16);
            sB1[nxt] = *(const uint4*)(b_src1 + (kb + 3) * 16);
        }
        v8bf a_hi = *(const v8bf*)(sm + cur * 9216 + arow * 24 + k8);
        v8bf a_lo = *(const v8bf*)(sm + cur * 9216 + 1536 + arow * 24 + k8);
#pragma unroll
        for (int t = 0; t < 2; ++t) {
            v8bf b_hi = *(const v8bf*)(sm + cur * 9216 + 3072 + (brow0 + t * 32) * 24 + k8);
            v8bf b_lo = *(const v8bf*)(sm + cur * 9216 + 6144 + (brow0 + t * 32) * 24 + k8);
            acc[t] = __builtin_amdgcn_mfma_f32_32x32x16_bf16(a_hi, b_hi, acc[t], 0, 0, 0);
            acc[t] = __builtin_amdgcn_mfma_f32_32x32x16_bf16(a_lo, b_hi, acc[t], 0, 0, 0);
            acc[t] = __builtin_amdgcn_mfma_f32_32x32x16_bf16(a_hi, b_lo, acc[t], 0, 0, 0);
        }
        __syncthreads();
    }

    // ---- single full-Gram dump: Ds_full[64][133] (2-way banks, free)
    float (*Ds)[133] = (float(*)[133])smem;          // 34048 B <= 36864
#pragma unroll
    for (int t = 0; t < 2; ++t)
#pragma unroll
        for (int r = 0; r < 16; ++r) {
            int row = (w & 1) * 32 + (r & 3) + 8 * (r >> 2) + 4 * (lane >> 5);
            int col = (w >> 1) * 64 + t * 32 + (lane & 31);
            Ds[row][col] = acc[t][r];
        }
    __syncthreads();

    // ---- selection: thread (q = tid&63, ch = tid>>6) scans its 32 cands in
    // ascending index order; top-9 stays in registers (VALU-only inserts).
    int sq_ = tid & 63, sch = tid >> 6;
    float sqqv = sqq_s[sq_];
    float dv[32], cvv[32];
#pragma unroll
    for (int qt = 0; qt < 4; ++qt)
#pragma unroll
        for (int j8 = 0; j8 < 8; ++j8) {
            int c = qt * 32 + sch * 8 + j8;
            dv[qt * 8 + j8] = Ds[sq_][c];
            cvv[qt * 8 + j8] = sqc_s[c];
        }
    float pd[KNN]; int pi[KNN];
#pragma unroll
    for (int j = 0; j < KNN; ++j) { pd[j] = __builtin_inff(); pi[j] = -1; }
#pragma unroll
    for (int qt = 0; qt < 4; ++qt)
#pragma unroll
        for (int j8 = 0; j8 < 8; ++j8) {
            int c = qt * 32 + sch * 8 + j8;
            float d = (sqqv - 2.0f * dv[qt * 8 + j8]) + cvv[qt * 8 + j8];  // inf pad
            if (d < pd[KNN - 1]) {
                pd[KNN - 1] = d; pi[KNN - 1] = gs + c0 + c;
#pragma unroll
                for (int j = KNN - 1; j > 0; --j) {
                    if (pd[j] < pd[j - 1]) {
                        float tf = pd[j]; pd[j] = pd[j - 1]; pd[j - 1] = tf;
                        int tn = pi[j]; pi[j] = pi[j - 1]; pi[j - 1] = tn;
                    }
                }
            }
        }
    __syncthreads();                     // all Ds reads done -> overlay lists

    float (*ld)[KNN][65] = (float(*)[KNN][65])smem;                    // 9360
    int   (*li)[KNN][65] = (int(*)[KNN][65])(smem + 9360);             // 9360
#pragma unroll
    for (int j = 0; j < KNN; ++j) { ld[sch][j][sq_] = pd[j]; li[sch][j][sq_] = pi[j]; }
    __syncthreads();

    // single serial merge: preload ALL 4x9 (d,i) -> registers, then
    // branch-local insertion merge (no load on the critical compare path).
    if (tid < 64) {
        float dL[4][KNN]; int iL[4][KNN];
#pragma unroll
        for (int ch = 0; ch < 4; ++ch)
#pragma unroll
            for (int j = 0; j < KNN; ++j) {
                dL[ch][j] = ld[ch][j][tid];
                iL[ch][j] = li[ch][j][tid];
            }
        float td[KNN]; int ti[KNN];
#pragma unroll
        for (int j = 0; j < KNN; ++j) { td[j] = __builtin_inff(); ti[j] = -1; }
#pragma unroll
        for (int ch = 0; ch < 4; ++ch) {
#pragma unroll
            for (int j0 = 0; j0 < KNN; ++j0) {
                float d = dL[ch][j0];
                if (!(d < td[KNN - 1])) break;   // sorted: rest can't insert
                td[KNN - 1] = d; ti[KNN - 1] = iL[ch][j0];
#pragma unroll
                for (int j = KNN - 1; j > 0; --j) {
                    if (td[j] < td[j - 1]) {
                        float tf = td[j]; td[j] = td[j - 1]; td[j - 1] = tf;
                        int tn = ti[j]; ti[j] = ti[j - 1]; ti[j - 1] = tn;
                    }
                }
            }
        }
        if (tid < nq) {
            int q = gs + q0 + tid;
            size_t base = ((size_t)q * NSPL + split) * PKS;
#pragma unroll
            for (int j = 0; j < KNN; ++j) { pk_d[base + j] = td[j]; pk_i[base + j] = ti[j]; }
        }
    }
}

// ---------------------------------------------------------------- merge + deg + W-transpose
// blocks 0..127: merge partial lists (64 q each) — stride-12 padded lists,
// float4/int4 register preload, branch-local early-break merge.
// blocks 128..199: build bf16 W0^T/W1^T into the dead xl region.
__global__ __launch_bounds__(64) void merge_kernel(
    const float* __restrict__ pk_d, const int* __restrict__ pk_i,
    int* __restrict__ edges, int* __restrict__ deg,
    const float* __restrict__ W0, const float* __restrict__ W1,
    unsigned short* __restrict__ wt)
{
    __shared__ float wtile[32][33];
    int tid = threadIdx.x;
    if (blockIdx.x >= 128) {             // ---- W transpose path
        int wid = blockIdx.x - 128;      // 0..71
        int mat = wid / 36, rem2 = wid % 36;
        int k0 = (rem2 / 6) * 32, n0 = (rem2 % 6) * 32;
        const float* W = mat ? W1 : W0;
#pragma unroll
        for (int p = 0; p < 4; ++p) {
            int idx = p * 64 + tid;
            int k = idx >> 3, n4 = (idx & 7) * 4;
            *(float4*)&wtile[k][n4] =
                *(const float4*)(W + (size_t)(k0 + k) * CF + n0 + n4);
        }
        __syncthreads();
#pragma unroll
        for (int p = 0; p < 4; ++p) {
            int idx = p * 64 + tid;
            int n = idx >> 3, k4 = (idx & 7) * 4;
            ushort4 h;
            h.x = f2bf(wtile[k4 + 0][n]); h.y = f2bf(wtile[k4 + 1][n]);
            h.z = f2bf(wtile[k4 + 2][n]); h.w = f2bf(wtile[k4 + 3][n]);
            *(ushort4*)(wt + (size_t)mat * 36864 + (size_t)(n0 + n) * CF + k0 + k4) = h;
        }
        return;
    }
    int q = blockIdx.x * 64 + tid;
    float td[KNN]; int ti[KNN];
#pragma unroll
    for (int j = 0; j < KNN; ++j) { td[j] = __builtin_inff(); ti[j] = -1; }
#pragma unroll
    for (int sb = 0; sb < 2; ++sb) {     // 2 batches of 4 splits, reg-preloaded
        float sd[4][KNN]; int si[4][KNN];
#pragma unroll
        for (int s2 = 0; s2 < 4; ++s2) {
            int s = sb * 4 + s2;         // compile-time (sb,s2 unrolled)
            const float* pd = pk_d + ((size_t)q * NSPL + s) * PKS;
            const int*   pp = pk_i + ((size_t)q * NSPL + s) * PKS;
            float4 d0 = *(const float4*)pd;
            float4 d1 = *(const float4*)(pd + 4);
            sd[s2][0] = d0.x; sd[s2][1] = d0.y; sd[s2][2] = d0.z; sd[s2][3] = d0.w;
            sd[s2][4] = d1.x; sd[s2][5] = d1.y; sd[s2][6] = d1.z; sd[s2][7] = d1.w;
            sd[s2][8] = pd[8];
            int4 i0 = *(const int4*)pp;
            int4 i1 = *(const int4*)(pp + 4);
            si[s2][0] = i0.x; si[s2][1] = i0.y; si[s2][2] = i0.z; si[s2][3] = i0.w;
            si[s2][4] = i1.x; si[s2][5] = i1.y; si[s2][6] = i1.z; si[s2][7] = i1.w;
            si[s2][8] = pp[8];
        }
#pragma unroll
        for (int s2 = 0; s2 < 4; ++s2) { // split order = index order (stable)
#pragma unroll
            for (int j0 = 0; j0 < KNN; ++j0) {
                float d = sd[s2][j0];
                if (!(d < td[KNN - 1])) break;   // sorted: rest can't insert
                td[KNN - 1] = d; ti[KNN - 1] = si[s2][j0];
#pragma unroll
                for (int j = KNN - 1; j > 0; --j) {
                    if (td[j] < td[j - 1]) {
                        float tf = td[j]; td[j] = td[j - 1]; td[j - 1] = tf;
                        int tn = ti[j]; ti[j] = ti[j - 1]; ti[j - 1] = tn;
                    }
                }
            }
        }
    }
#pragma unroll
    for (int j = 0; j < KNN; ++j) {
        int id = ti[j];                   // -1 <=> invalid (d == inf)
        edges[q * KNN + j] = id;
        if (id >= 0 && id != q) atomicAdd(&deg[id], 1);
    }
}

// ---------------------------------------------------------------- fused Tx1 + out GEMM (MFMA)
// One block per 16-row stripe (512 blocks). out = A0@W0 + A1@W1 + bias via
// mfma_f32_16x16x32_bf16, K=384 fused. R17: Wts double-buffered + depth-2
// W register prefetch (W loads are input-independent -> issued at kernel
// top); ONE barrier per kt (6) instead of 12, W L2 latency hidden.
// C/D (m89-verified): col=lane&15, row=(lane>>4)*4+reg. Wave w: n-tiles 3w..3w+2.
__global__ __launch_bounds__(256, 2) void out_kernel(
    const unsigned short* __restrict__ xh, const unsigned short* __restrict__ wt,
    const int* __restrict__ edges, const int* __restrict__ deg,
    const float* __restrict__ bias, float* __restrict__ out)
{
    __shared__ __align__(16) unsigned short A0s[16][200];  // xf rows  (padded)
    __shared__ __align__(16) unsigned short A1s[16][200];  // Tx1 rows (padded)
    __shared__ unsigned short Wts[2][2][CF][32];           // dbuf W^T k-slices (49152 B)
    __shared__ float coef_s[16][KNN];
    __shared__ int   nb_s[16][KNN];

    int r0 = blockIdx.x * 16;
    int tid = threadIdx.x;

    // per-thread W-staging role (fixed): 6 of 1536 uint4 per k-slice
#define LDW(dst, kt_)                                                          \
    _Pragma("unroll")                                                          \
    for (int p = 0; p < 6; ++p) {                                              \
        int f = p * 256 + tid;                                                 \
        int mat = f / 768, n = (f % 768) / 4, k16 = (f % 4) * 8;               \
        dst[p] = *(const uint4*)(wt + (size_t)mat * 36864 + (size_t)n * CF     \
                                 + (kt_) * 32 + k16);                          \
    }
#define STW(buf_, src)                                                         \
    _Pragma("unroll")                                                          \
    for (int p = 0; p < 6; ++p) {                                              \
        int f = p * 256 + tid;                                                 \
        int mat = f / 768, n = (f % 768) / 4, k16 = (f % 4) * 8;               \
        *(uint4*)&Wts[buf_][mat][n][k16] = src[p];                             \
    }

    uint4 wr[2][6];
    LDW(wr[0], 0);                       // kt0 W loads in flight immediately

    // stage xf rows (bf16 copy): 16 x 24 uint4 = 384
    for (int t = tid; t < 384; t += 256) {
        int i = t / 24, c8 = (t % 24) * 8;
        *(uint4*)&A0s[i][c8] = *(const uint4*)(xh + (size_t)(r0 + i) * CF + c8);
    }
    // coefficients: one (row, edge) per thread
    if (tid < 16 * KNN) {
        int i = tid / KNN, j = tid % KNN;
        int q = r0 + i;
        int id = edges[q * KNN + j];
        float cf = 0.0f; int s = q;
        if (id >= 0 && id != q) { cf = -disf(deg[id]) * disf(deg[q]); s = id; }
        coef_s[i][j] = cf; nb_s[i][j] = s;
    }
    LDW(wr[1], 1);
    __syncthreads();
    // gather Tx1 rows: role = (i, 8-ch block) -> 384 roles, uint4 per neighbor
    for (int e = tid; e < 16 * CF / 8; e += 256) {
        int i = e / 24, c8 = (e % 24) * 8;
        float a[8];
#pragma unroll
        for (int j = 0; j < 8; ++j) a[j] = 0.0f;
#pragma unroll
        for (int t = 0; t < KNN; ++t) {
            float cf = coef_s[i][t];
            uint4 v = *(const uint4*)(xh + (size_t)nb_s[i][t] * CF + c8);
            const unsigned short* pv = (const unsigned short*)&v;
#pragma unroll
            for (int j = 0; j < 8; ++j) a[j] = fmaf(cf, bf2f(pv[j]), a[j]);
        }
        uint4 hv;
        hv.x = (unsigned)f2bf(a[0]) | ((unsigned)f2bf(a[1]) << 16);
        hv.y = (unsigned)f2bf(a[2]) | ((unsigned)f2bf(a[3]) << 16);
        hv.z = (unsigned)f2bf(a[4]) | ((unsigned)f2bf(a[5]) << 16);
        hv.w = (unsigned)f2bf(a[6]) | ((unsigned)f2bf(a[7]) << 16);
        *(uint4*)&A1s[i][c8] = hv;
    }
    STW(0, wr[0]);                       // publish kt0 (vmcnt long covered)
    LDW(wr[0], 2);                       // refill slot0 with kt2
    __syncthreads();                     // A1s + Wts[0] ready

    int lane = tid & 63, w = tid >> 6;
    int m = lane & 15;                   // A row / B col index
    int kq = (lane >> 4) * 8;            // k offset within 32-slice
    f32x4 acc[3];
#pragma unroll
    for (int t = 0; t < 3; ++t)
#pragma unroll
        for (int r = 0; r < 4; ++r) acc[t][r] = 0.0f;

    // invariant at top of iter kt: Wts[kt&1] holds kt; wr[(kt+1)&1] holds
    // kt+1; wr[kt&1] holds kt+2. ONE barrier per iteration.
#pragma unroll
    for (int kt = 0; kt < 6; ++kt) {
        const int cur = kt & 1, nxt = cur ^ 1;
        if (kt < 5) { STW(nxt, wr[nxt]); }
        if (kt < 3) { LDW(wr[nxt], kt + 3); }
        v8bf a0 = *(const v8bf*)&A0s[m][kt * 32 + kq];
        v8bf a1 = *(const v8bf*)&A1s[m][kt * 32 + kq];
#pragma unroll
        for (int t3 = 0; t3 < 3; ++t3) {
            int n0 = w * 48 + t3 * 16;
            v8bf w0 = *(const v8bf*)&Wts[cur][0][n0 + m][kq];
            v8bf w1 = *(const v8bf*)&Wts[cur][1][n0 + m][kq];
            acc[t3] = __builtin_amdgcn_mfma_f32_16x16x32_bf16(a0, w0, acc[t3], 0, 0, 0);
            acc[t3] = __builtin_amdgcn_mfma_f32_16x16x32_bf16(a1, w1, acc[t3], 0, 0, 0);
        }
        __syncthreads();
    }

    int col = lane & 15, rb = (lane >> 4) * 4;
#pragma unroll
    for (int t3 = 0; t3 < 3; ++t3) {
        int n0 = w * 48 + t3 * 16;
        float bv = bias[n0 + col];
#pragma unroll
        for (int r = 0; r < 4; ++r)
            out[(size_t)(r0 + rb + r) * CF + n0 + col] = acc[t3][r] + bv;
    }
#undef LDW
#undef STW
}

// ---------------------------------------------------------------- launch
extern "C" void kernel_launch(void* const* d_in, const int* in_sizes, int n_in,
                              void* d_out, int out_size, void* d_ws, size_t ws_size,
                              hipStream_t stream)
{
    const float* x    = (const float*)d_in[0];
    const float* W0   = (const float*)d_in[1];
    const float* W1   = (const float*)d_in[2];
    const float* bias = (const float*)d_in[3];
    float* out = (float*)d_out;

    // Workspace: 6,651,904 B (known-safe total).
    char* ws = (char*)d_ws;
    unsigned short* xh = (unsigned short*)ws; ws += (size_t)NN * CF * 2;  // 3,145,728
    unsigned short* xl = (unsigned short*)ws; ws += (size_t)NN * CF * 2;  // 3,145,728
    float* sq    = (float*)ws;  ws += (size_t)NN * 4;        //    32,768
    int*   deg   = (int*)ws;    ws += (size_t)NN * 4;        //    32,768
    int*   edges = (int*)ws;    ws += (size_t)NN * KNN * 4;  //   294,912

    // xl is dead after knn -> reuse its space for bf16 W0^T/W1^T (147 KB).
    unsigned short* wt = xl;

    // Partial top-k lists live in d_out (exactly 6.29 MB with PKS=12); d_out
    // is fully overwritten by out_kernel afterwards, every call.
    float* pk_d = out;                                        // NN*NSPL*PKS fl
    int*   pk_i = (int*)(out + (size_t)NN * NSPL * PKS);      // NN*NSPL*PKS int

    hipLaunchKernelGGL(transpose_kernel, dim3(8, 16), dim3(256), 0, stream,
                       x, xh, xl, sq, deg);
    hipLaunchKernelGGL(knn_kernel, dim3(1152), dim3(256), 0, stream,
                       xh, xl, sq, pk_d, pk_i);
    hipLaunchKernelGGL(merge_kernel, dim3(200), dim3(64), 0, stream,
                       pk_d, pk_i, edges, deg, W0, W1, wt);
    hipLaunchKernelGGL(out_kernel, dim3(512), dim3(256), 0, stream,
                       xh, wt, edges, deg, bias, out);
}

// Round 3
// 121.686 us; speedup vs baseline: 1.4174x; 1.4174x over previous
//
#include <hip/hip_runtime.h>
#include <math.h>

#define NN 8192
#define CF 192
#define KNN 9
#define NSPL 8
#define PKS 12   // padded partial-list stride (16B-aligned for float4 preloads)

typedef __bf16 v8bf __attribute__((ext_vector_type(8)));
typedef float f32x16 __attribute__((ext_vector_type(16)));
typedef float f32x4 __attribute__((ext_vector_type(4)));

__device__ __forceinline__ int group_start(int g) {
    // smallest i with batch[i]==g :  ceil(8191*g/8), capped at 8192
    int s = (8191 * g + 7) >> 3;
    return s > 8192 ? 8192 : s;
}

__device__ __forceinline__ float disf(int d) {
    return d > 0 ? 1.0f / sqrtf((float)d) : 0.0f;
}

__device__ __forceinline__ unsigned short f2bf(float f) {
    unsigned u = __float_as_uint(f);
    unsigned r = (u + 0x7FFFu + ((u >> 16) & 1u)) >> 16;   // round-nearest-even
    return (unsigned short)r;
}
__device__ __forceinline__ float bf2f(unsigned short h) {
    return __uint_as_float(((unsigned)h) << 16);
}

// ---------------------------------------------------------------- transpose + split + sq
// x [8,192,32,32] -> xh/xl [8192][192] bf16 (hi/lo split, computed once).
// One block owns 64 nodes x all 192 ch -> sq computed locally; deg zeroed.
__global__ __launch_bounds__(256) void transpose_kernel(
    const float* __restrict__ x, unsigned short* __restrict__ xh,
    unsigned short* __restrict__ xl, float* __restrict__ sq,
    int* __restrict__ deg)
{
    __shared__ float tile[32][65];
    int b = blockIdx.x, ht = blockIdx.y;         // 8 x 16 blocks
    int hw0 = ht * 64;
    int tid = threadIdx.x;
    if (tid < 64) deg[(b * 16 + ht) * 64 + tid] = 0;

    float sacc[8];
#pragma unroll
    for (int p = 0; p < 8; ++p) sacc[p] = 0.0f;

    for (int ct = 0; ct < 6; ++ct) {
        int c0 = ct * 32;
        __syncthreads();
#pragma unroll
        for (int p = 0; p < 8; ++p) {
            int c  = p * 4 + (tid >> 6);
            int hw = tid & 63;
            tile[c][hw] = x[(size_t)b * 196608 + (size_t)(c0 + c) * 1024 + hw0 + hw];
        }
        __syncthreads();
#pragma unroll
        for (int p = 0; p < 8; ++p) {
            int hw = p * 8 + (tid >> 5);
            int cc = tid & 31;
            float v = tile[cc][hw];
            size_t o = (size_t)(b * 1024 + hw0 + hw) * CF + c0 + cc;
            unsigned short h = f2bf(v);
            xh[o] = h;
            xl[o] = f2bf(v - bf2f(h));
            sacc[p] = fmaf(v, v, sacc[p]);
        }
    }
#pragma unroll
    for (int p = 0; p < 8; ++p) {
        float s = sacc[p];
#pragma unroll
        for (int off = 16; off > 0; off >>= 1) s += __shfl_xor(s, off, 32);
        if ((tid & 31) == 0)
            sq[(size_t)(b * 1024 + hw0 + p * 8 + (tid >> 5))] = s;
    }
}

// ---------------------------------------------------------------- kNN partial (MFMA)
// grid: 9 groups x 16 query-blocks(64 q) x 8 candidate-splits(128 c) = 1152.
// R18 (post-mortem of R17: rotating prefetch ARRAYS in unrolled loops spilled
// to scratch -> 150 MB of scratch traffic. Spill-proof re-do):
//  (a) BK=32 K-loop: 6 rolling (NOT unrolled) iterations, 2 barriers each
//      (12 vs R16's 24). Staging state = 6 NAMED uint4 regs + 6 precomputed
//      int offsets; kb+1 loads issued right after the visibility barrier.
//      Row pad 40 shorts: same 4-way frag-read aliasing as R16's stride 24,
//      16B-aligned ds writes.
//  (b) single full-Gram dump Ds[64][133] (conflict-free write+column read) in
//      the dead staging LDS: selection barriers 10 -> 3. Selection itself =
//      R16's proven per-quarter dv[8]/cv[8] register batches (small live
//      ranges), persistent top-9, single wave0 merge.
// C/D layout (HW-verified): col=lane&31, row=(reg&3)+8*(reg>>2)+4*(lane>>5).
__global__ __launch_bounds__(256, 2) void knn_kernel(
    const unsigned short* __restrict__ xh, const unsigned short* __restrict__ xl,
    const float* __restrict__ sq,
    float* __restrict__ pk_d, int* __restrict__ pk_i)
{
    int bid = blockIdx.x;
    int g = bid >> 7;
    int rem = bid & 127;
    int qb = rem >> 3;
    int split = rem & 7;
    int gs = group_start(g);
    int gsize = group_start(g + 1) - gs;
    int q0 = qb * 64;
    int nq = gsize - q0; if (nq > 64) nq = 64;
    if (nq <= 0) return;                 // block-uniform; q's covered elsewhere
    int c0 = split * 128;
    int ncc = gsize - c0; if (ncc > 128) ncc = 128;

    int tid = threadIdx.x;

    if (ncc <= 0) {                      // block-uniform: empty split
        if (tid < nq) {
            int q = gs + q0 + tid;
            size_t base = ((size_t)q * NSPL + split) * PKS;
#pragma unroll
            for (int j = 0; j < KNN; ++j) { pk_d[base + j] = __builtin_inff(); pk_i[base + j] = -1; }
        }
        return;
    }

    // staging (30720 B, BK=32, pad 40) overlaid by Ds[64][133] (34048 B),
    // then by the merge lists (18720 B).
    __shared__ __align__(16) char smem[34048];
    unsigned short* sm = (unsigned short*)smem;
    // short-offsets: Ah[64][40] @0, Al @2560, Bh[128][40] @5120, Bl @10240
    __shared__ float sqc_s[128];
    __shared__ float sqq_s[64];

    int lane = tid & 63, w = tid >> 6;
    int arow = (w & 1) * 32 + (lane & 31);
    int k8 = (lane >> 5) * 8;
    int brow0 = (w >> 1) * 64 + (lane & 31);

    if (tid < 64) {
        int qo = q0 + tid; if (qo > gsize - 1) qo = gsize - 1;
        sqq_s[tid] = sq[gs + qo];
    }
    if (tid < 128) {
        sqc_s[tid] = (tid < ncc) ? sq[gs + c0 + tid] : __builtin_inff();
    }

    // ---- fixed staging roles, 6 per thread (p = 0..5), all offsets in shorts.
    // p0: A-hi row tid>>2, p1: A-lo; p2/p3: B-hi rows 0..63 / 64..127;
    // p4/p5: B-lo same rows. Each role copies one 16 B quarter (q4 = tid&3).
    int rr = tid >> 2, q4 = tid & 3;
    int aq = q0 + rr; if (aq > gsize - 1) aq = gsize - 1;
    int cqA = c0 + rr;      if (cqA > gsize - 1) cqA = gsize - 1;
    int cqB = c0 + 64 + rr; if (cqB > gsize - 1) cqB = gsize - 1;
    int g0 = (gs + aq)  * CF + q4 * 8;           // xh (A hi)
    int g1 = g0 + NN * CF;                       // xl (A lo)
    int g2 = (gs + cqA) * CF + q4 * 8;           // xh (B hi, rows 0..63)
    int g3 = (gs + cqB) * CF + q4 * 8;           // xh (B hi, rows 64..127)
    int g4 = g2 + NN * CF;                       // xl
    int g5 = g3 + NN * CF;                       // xl
    int s0 = rr * 40 + q4 * 8;
    int s1 = s0 + 2560;
    int s2 = 5120 + s0;
    int s3 = s2 + 2560;
    int s4 = s2 + 5120;
    int s5 = s3 + 5120;

    f32x16 acc[2];
#pragma unroll
    for (int t = 0; t < 2; ++t)
#pragma unroll
        for (int r = 0; r < 16; ++r) acc[t][r] = 0.0f;

    // named prefetch regs (NO arrays, NO rotation -> no scratch)
    uint4 d0, d1, d2, d3, d4, d5;
    d0 = *(const uint4*)(xh + g0); d1 = *(const uint4*)(xh + g1);
    d2 = *(const uint4*)(xh + g2); d3 = *(const uint4*)(xh + g3);
    d4 = *(const uint4*)(xh + g4); d5 = *(const uint4*)(xh + g5);

    for (int kb = 0; kb < 6; ++kb) {     // rolling; 2 barriers per iter
        *(uint4*)(sm + s0) = d0; *(uint4*)(sm + s1) = d1;
        *(uint4*)(sm + s2) = d2; *(uint4*)(sm + s3) = d3;
        *(uint4*)(sm + s4) = d4; *(uint4*)(sm + s5) = d5;
        __syncthreads();                 // staging visible
        if (kb < 5) {                    // issue kb+1; hides under 12 MFMAs
            int o = (kb + 1) * 32;
            d0 = *(const uint4*)(xh + g0 + o); d1 = *(const uint4*)(xh + g1 + o);
            d2 = *(const uint4*)(xh + g2 + o); d3 = *(const uint4*)(xh + g3 + o);
            d4 = *(const uint4*)(xh + g4 + o); d5 = *(const uint4*)(xh + g5 + o);
        }
#pragma unroll
        for (int h = 0; h < 2; ++h) {    // two 16-k halves of the 32-k tile
            int ao = arow * 40 + h * 16 + k8;
            v8bf a_hi = *(const v8bf*)(sm + ao);
            v8bf a_lo = *(const v8bf*)(sm + 2560 + ao);
#pragma unroll
            for (int t = 0; t < 2; ++t) {
                int bo = 5120 + (brow0 + t * 32) * 40 + h * 16 + k8;
                v8bf b_hi = *(const v8bf*)(sm + bo);
                v8bf b_lo = *(const v8bf*)(sm + 5120 + bo);
                acc[t] = __builtin_amdgcn_mfma_f32_32x32x16_bf16(a_hi, b_hi, acc[t], 0, 0, 0);
                acc[t] = __builtin_amdgcn_mfma_f32_32x32x16_bf16(a_lo, b_hi, acc[t], 0, 0, 0);
                acc[t] = __builtin_amdgcn_mfma_f32_32x32x16_bf16(a_hi, b_lo, acc[t], 0, 0, 0);
            }
        }
        __syncthreads();                 // frag reads done -> next write safe
    }

    // ---- single full-Gram dump: Ds[64][133] (bank-conflict-free both ways)
    float (*Ds)[133] = (float(*)[133])smem;          // 34048 B
#pragma unroll
    for (int t = 0; t < 2; ++t)
#pragma unroll
        for (int r = 0; r < 16; ++r) {
            int row = (w & 1) * 32 + (r & 3) + 8 * (r >> 2) + 4 * (lane >> 5);
            int col = (w >> 1) * 64 + t * 32 + (lane & 31);
            Ds[row][col] = acc[t][r];
        }
    __syncthreads();

    // ---- selection: thread (q = tid&63, ch = tid>>6) scans its 32 cands in
    // ascending index order, 4 batches of 8 (small live ranges; R16-proven).
    int sq_ = tid & 63, sch = tid >> 6;
    float sqqv = sqq_s[sq_];
    float pd[KNN]; int pi[KNN];
#pragma unroll
    for (int j = 0; j < KNN; ++j) { pd[j] = __builtin_inff(); pi[j] = -1; }
#pragma unroll
    for (int qt = 0; qt < 4; ++qt) {
        float dv[8], cv[8];
#pragma unroll
        for (int j8 = 0; j8 < 8; ++j8) {
            int c = qt * 32 + sch * 8 + j8;
            dv[j8] = Ds[sq_][c];
            cv[j8] = sqc_s[c];
        }
#pragma unroll
        for (int j8 = 0; j8 < 8; ++j8) {
            float d = (sqqv - 2.0f * dv[j8]) + cv[j8];        // inf pad
            if (d < pd[KNN - 1]) {
                pd[KNN - 1] = d; pi[KNN - 1] = gs + c0 + qt * 32 + sch * 8 + j8;
#pragma unroll
                for (int j = KNN - 1; j > 0; --j) {
                    if (pd[j] < pd[j - 1]) {
                        float tf = pd[j]; pd[j] = pd[j - 1]; pd[j - 1] = tf;
                        int tn = pi[j]; pi[j] = pi[j - 1]; pi[j - 1] = tn;
                    }
                }
            }
        }
    }
    __syncthreads();                     // all Ds reads done -> overlay lists

    float (*ld)[KNN][65] = (float(*)[KNN][65])smem;                    // 9360
    int   (*li)[KNN][65] = (int(*)[KNN][65])(smem + 9360);             // 9360
#pragma unroll
    for (int j = 0; j < KNN; ++j) { ld[sch][j][sq_] = pd[j]; li[sch][j][sq_] = pi[j]; }
    __syncthreads();

    // single serial merge: preload ALL 4x9 (d,i) -> registers, then
    // branch-local insertion merge (no load on the critical compare path).
    if (tid < 64) {
        float dL[4][KNN]; int iL[4][KNN];
#pragma unroll
        for (int ch = 0; ch < 4; ++ch)
#pragma unroll
            for (int j = 0; j < KNN; ++j) {
                dL[ch][j] = ld[ch][j][tid];
                iL[ch][j] = li[ch][j][tid];
            }
        float td[KNN]; int ti[KNN];
#pragma unroll
        for (int j = 0; j < KNN; ++j) { td[j] = __builtin_inff(); ti[j] = -1; }
#pragma unroll
        for (int ch = 0; ch < 4; ++ch) {
#pragma unroll
            for (int j0 = 0; j0 < KNN; ++j0) {
                float d = dL[ch][j0];
                if (!(d < td[KNN - 1])) break;   // sorted: rest can't insert
                td[KNN - 1] = d; ti[KNN - 1] = iL[ch][j0];
#pragma unroll
                for (int j = KNN - 1; j > 0; --j) {
                    if (td[j] < td[j - 1]) {
                        float tf = td[j]; td[j] = td[j - 1]; td[j - 1] = tf;
                        int tn = ti[j]; ti[j] = ti[j - 1]; ti[j - 1] = tn;
                    }
                }
            }
        }
        if (tid < nq) {
            int q = gs + q0 + tid;
            size_t base = ((size_t)q * NSPL + split) * PKS;
#pragma unroll
            for (int j = 0; j < KNN; ++j) { pk_d[base + j] = td[j]; pk_i[base + j] = ti[j]; }
        }
    }
}

// ---------------------------------------------------------------- merge + deg + W-transpose
// blocks 0..127: merge partial lists (64 q each) — stride-12 padded lists,
// float4/int4 register preload, branch-local early-break merge.
// blocks 128..199: build bf16 W0^T/W1^T into the dead xl region.
__global__ __launch_bounds__(64) void merge_kernel(
    const float* __restrict__ pk_d, const int* __restrict__ pk_i,
    int* __restrict__ edges, int* __restrict__ deg,
    const float* __restrict__ W0, const float* __restrict__ W1,
    unsigned short* __restrict__ wt)
{
    __shared__ float wtile[32][33];
    int tid = threadIdx.x;
    if (blockIdx.x >= 128) {             // ---- W transpose path
        int wid = blockIdx.x - 128;      // 0..71
        int mat = wid / 36, rem2 = wid % 36;
        int k0 = (rem2 / 6) * 32, n0 = (rem2 % 6) * 32;
        const float* W = mat ? W1 : W0;
#pragma unroll
        for (int p = 0; p < 4; ++p) {
            int idx = p * 64 + tid;
            int k = idx >> 3, n4 = (idx & 7) * 4;
            *(float4*)&wtile[k][n4] =
                *(const float4*)(W + (size_t)(k0 + k) * CF + n0 + n4);
        }
        __syncthreads();
#pragma unroll
        for (int p = 0; p < 4; ++p) {
            int idx = p * 64 + tid;
            int n = idx >> 3, k4 = (idx & 7) * 4;
            ushort4 h;
            h.x = f2bf(wtile[k4 + 0][n]); h.y = f2bf(wtile[k4 + 1][n]);
            h.z = f2bf(wtile[k4 + 2][n]); h.w = f2bf(wtile[k4 + 3][n]);
            *(ushort4*)(wt + (size_t)mat * 36864 + (size_t)(n0 + n) * CF + k0 + k4) = h;
        }
        return;
    }
    int q = blockIdx.x * 64 + tid;
    float td[KNN]; int ti[KNN];
#pragma unroll
    for (int j = 0; j < KNN; ++j) { td[j] = __builtin_inff(); ti[j] = -1; }
#pragma unroll
    for (int sb = 0; sb < 2; ++sb) {     // 2 batches of 4 splits, reg-preloaded
        float sd[4][KNN]; int si[4][KNN];
#pragma unroll
        for (int s2 = 0; s2 < 4; ++s2) {
            int s = sb * 4 + s2;         // compile-time (sb,s2 unrolled)
            const float* pd = pk_d + ((size_t)q * NSPL + s) * PKS;
            const int*   pp = pk_i + ((size_t)q * NSPL + s) * PKS;
            float4 d0 = *(const float4*)pd;
            float4 d1 = *(const float4*)(pd + 4);
            sd[s2][0] = d0.x; sd[s2][1] = d0.y; sd[s2][2] = d0.z; sd[s2][3] = d0.w;
            sd[s2][4] = d1.x; sd[s2][5] = d1.y; sd[s2][6] = d1.z; sd[s2][7] = d1.w;
            sd[s2][8] = pd[8];
            int4 i0 = *(const int4*)pp;
            int4 i1 = *(const int4*)(pp + 4);
            si[s2][0] = i0.x; si[s2][1] = i0.y; si[s2][2] = i0.z; si[s2][3] = i0.w;
            si[s2][4] = i1.x; si[s2][5] = i1.y; si[s2][6] = i1.z; si[s2][7] = i1.w;
            si[s2][8] = pp[8];
        }
#pragma unroll
        for (int s2 = 0; s2 < 4; ++s2) { // split order = index order (stable)
#pragma unroll
            for (int j0 = 0; j0 < KNN; ++j0) {
                float d = sd[s2][j0];
                if (!(d < td[KNN - 1])) break;   // sorted: rest can't insert
                td[KNN - 1] = d; ti[KNN - 1] = si[s2][j0];
#pragma unroll
                for (int j = KNN - 1; j > 0; --j) {
                    if (td[j] < td[j - 1]) {
                        float tf = td[j]; td[j] = td[j - 1]; td[j - 1] = tf;
                        int tn = ti[j]; ti[j] = ti[j - 1]; ti[j - 1] = tn;
                    }
                }
            }
        }
    }
#pragma unroll
    for (int j = 0; j < KNN; ++j) {
        int id = ti[j];                   // -1 <=> invalid (d == inf)
        edges[q * KNN + j] = id;
        if (id >= 0 && id != q) atomicAdd(&deg[id], 1);
    }
}

// ---------------------------------------------------------------- fused Tx1 + out GEMM (MFMA)
// One block per 16-row stripe (512 blocks). out = A0@W0 + A1@W1 + bias via
// mfma_f32_16x16x32_bf16, K=384 fused. R16-proven form (R17's W prefetch
// arrays spilled -> reverted). Gather: one uint4 (8 bf16 ch) per neighbor.
// C/D (m89-verified): col=lane&15, row=(lane>>4)*4+reg. Wave w: n-tiles 3w..3w+2.
__global__ __launch_bounds__(256, 2) void out_kernel(
    const unsigned short* __restrict__ xh, const unsigned short* __restrict__ wt,
    const int* __restrict__ edges, const int* __restrict__ deg,
    const float* __restrict__ bias, float* __restrict__ out)
{
    __shared__ __align__(16) unsigned short A0s[16][200];  // xf rows  (padded)
    __shared__ __align__(16) unsigned short A1s[16][200];  // Tx1 rows (padded)
    __shared__ unsigned short Wts[2][CF][32];   // W^T k-slice (24576 B)
    __shared__ float coef_s[16][KNN];
    __shared__ int   nb_s[16][KNN];

    int r0 = blockIdx.x * 16;
    int tid = threadIdx.x;

    // stage xf rows (bf16 copy): 16 x 24 uint4 = 384
    for (int t = tid; t < 384; t += 256) {
        int i = t / 24, c8 = (t % 24) * 8;
        *(uint4*)&A0s[i][c8] = *(const uint4*)(xh + (size_t)(r0 + i) * CF + c8);
    }
    // coefficients: one (row, edge) per thread
    if (tid < 16 * KNN) {
        int i = tid / KNN, j = tid % KNN;
        int q = r0 + i;
        int id = edges[q * KNN + j];
        float cf = 0.0f; int s = q;
        if (id >= 0 && id != q) { cf = -disf(deg[id]) * disf(deg[q]); s = id; }
        coef_s[i][j] = cf; nb_s[i][j] = s;
    }
    __syncthreads();
    // gather Tx1 rows: role = (i, 8-ch block) -> 384 roles, uint4 per neighbor
    for (int e = tid; e < 16 * CF / 8; e += 256) {
        int i = e / 24, c8 = (e % 24) * 8;
        float a[8];
#pragma unroll
        for (int j = 0; j < 8; ++j) a[j] = 0.0f;
#pragma unroll
        for (int t = 0; t < KNN; ++t) {
            float cf = coef_s[i][t];
            uint4 v = *(const uint4*)(xh + (size_t)nb_s[i][t] * CF + c8);
            const unsigned short* pv = (const unsigned short*)&v;
#pragma unroll
            for (int j = 0; j < 8; ++j) a[j] = fmaf(cf, bf2f(pv[j]), a[j]);
        }
        uint4 hv;
        hv.x = (unsigned)f2bf(a[0]) | ((unsigned)f2bf(a[1]) << 16);
        hv.y = (unsigned)f2bf(a[2]) | ((unsigned)f2bf(a[3]) << 16);
        hv.z = (unsigned)f2bf(a[4]) | ((unsigned)f2bf(a[5]) << 16);
        hv.w = (unsigned)f2bf(a[6]) | ((unsigned)f2bf(a[7]) << 16);
        *(uint4*)&A1s[i][c8] = hv;
    }

    int lane = tid & 63, w = tid >> 6;
    int m = lane & 15;                   // A row / B col index
    int kq = (lane >> 4) * 8;            // k offset within 32-slice
    f32x4 acc[3];
#pragma unroll
    for (int t = 0; t < 3; ++t)
#pragma unroll
        for (int r = 0; r < 4; ++r) acc[t][r] = 0.0f;

    for (int kt = 0; kt < 6; ++kt) {     // K=192 in 32-slices, both mats fused
        __syncthreads();                 // kt=0: A1s ready; else Wts consumed
#pragma unroll
        for (int p = 0; p < 6; ++p) {    // stage Wts: 1536 uint4
            int f = p * 256 + tid;
            int mat = f / 768, n = (f % 768) / 4, k16 = (f % 4) * 8;
            *(uint4*)&Wts[mat][n][k16] =
                *(const uint4*)(wt + (size_t)mat * 36864 + (size_t)n * CF + kt * 32 + k16);
        }
        __syncthreads();
        v8bf a0 = *(const v8bf*)&A0s[m][kt * 32 + kq];
        v8bf a1 = *(const v8bf*)&A1s[m][kt * 32 + kq];
#pragma unroll
        for (int t3 = 0; t3 < 3; ++t3) {
            int n0 = w * 48 + t3 * 16;
            v8bf w0 = *(const v8bf*)&Wts[0][n0 + m][kq];
            v8bf w1 = *(const v8bf*)&Wts[1][n0 + m][kq];
            acc[t3] = __builtin_amdgcn_mfma_f32_16x16x32_bf16(a0, w0, acc[t3], 0, 0, 0);
            acc[t3] = __builtin_amdgcn_mfma_f32_16x16x32_bf16(a1, w1, acc[t3], 0, 0, 0);
        }
    }

    int col = lane & 15, rb = (lane >> 4) * 4;
#pragma unroll
    for (int t3 = 0; t3 < 3; ++t3) {
        int n0 = w * 48 + t3 * 16;
        float bv = bias[n0 + col];
#pragma unroll
        for (int r = 0; r < 4; ++r)
            out[(size_t)(r0 + rb + r) * CF + n0 + col] = acc[t3][r] + bv;
    }
}

// ---------------------------------------------------------------- launch
extern "C" void kernel_launch(void* const* d_in, const int* in_sizes, int n_in,
                              void* d_out, int out_size, void* d_ws, size_t ws_size,
                              hipStream_t stream)
{
    const float* x    = (const float*)d_in[0];
    const float* W0   = (const float*)d_in[1];
    const float* W1   = (const float*)d_in[2];
    const float* bias = (const float*)d_in[3];
    float* out = (float*)d_out;

    // Workspace: 6,651,904 B (known-safe total).
    char* ws = (char*)d_ws;
    unsigned short* xh = (unsigned short*)ws; ws += (size_t)NN * CF * 2;  // 3,145,728
    unsigned short* xl = (unsigned short*)ws; ws += (size_t)NN * CF * 2;  // 3,145,728
    float* sq    = (float*)ws;  ws += (size_t)NN * 4;        //    32,768
    int*   deg   = (int*)ws;    ws += (size_t)NN * 4;        //    32,768
    int*   edges = (int*)ws;    ws += (size_t)NN * KNN * 4;  //   294,912

    // xl is dead after knn -> reuse its space for bf16 W0^T/W1^T (147 KB).
    unsigned short* wt = xl;

    // Partial top-k lists live in d_out (exactly 6.29 MB with PKS=12); d_out
    // is fully overwritten by out_kernel afterwards, every call.
    float* pk_d = out;                                        // NN*NSPL*PKS fl
    int*   pk_i = (int*)(out + (size_t)NN * NSPL * PKS);      // NN*NSPL*PKS int

    hipLaunchKernelGGL(transpose_kernel, dim3(8, 16), dim3(256), 0, stream,
                       x, xh, xl, sq, deg);
    hipLaunchKernelGGL(knn_kernel, dim3(1152), dim3(256), 0, stream,
                       xh, xl, sq, pk_d, pk_i);
    hipLaunchKernelGGL(merge_kernel, dim3(200), dim3(64), 0, stream,
                       pk_d, pk_i, edges, deg, W0, W1, wt);
    hipLaunchKernelGGL(out_kernel, dim3(512), dim3(256), 0, stream,
                       xh, wt, edges, deg, bias, out);
}